// Round 1
// baseline (4061.584 us; speedup 1.0000x reference)
//
#include <hip/hip_runtime.h>
#include <math.h>

// ---------------- problem constants ----------------
#define Lsz   1024
#define Tsz   32
#define Bsz   64
#define DIN   300
#define REG   36
#define Rsz   128
#define R3sz  384
#define H3sz  3072

__device__ __forceinline__ float sigf(float x) { return 1.f / (1.f + __expf(-x)); }

// =====================================================================
// Generic tiled SGEMM: C[m][n] = sum_k A[m*lda+k] * W[n*ldw+woff+k] + bias[n]
// mode 0: C row-major (M x N).  mode 1: scatter to [(m%32)*N + n]*64 + m/32
// (i.e. [t][n][b] layout for m = b*32 + t).
// Block 256 threads, 64x64 tile, 4x4 register tile, K-chunk 16.
// =====================================================================
__global__ __launch_bounds__(256) void gemm_bias(
    const float* __restrict__ A, int lda,
    const float* __restrict__ W, int ldw, int woff,
    const float* __restrict__ bias,
    float* __restrict__ C, int M, int N, int K, int mode)
{
    __shared__ float As[16][68];
    __shared__ float Ws[16][68];
    int tid = threadIdx.x;
    int tx = tid & 15, ty = tid >> 4;
    int m0 = blockIdx.y * 64, n0 = blockIdx.x * 64;
    float acc[4][4];
#pragma unroll
    for (int i = 0; i < 4; i++)
#pragma unroll
        for (int j = 0; j < 4; j++) acc[i][j] = 0.f;

    for (int k0 = 0; k0 < K; k0 += 16) {
#pragma unroll
        for (int l = 0; l < 4; l++) {
            int e = l * 256 + tid;
            int kk = e & 15, mm = e >> 4;
            int m = m0 + mm, k = k0 + kk;
            As[kk][mm] = (m < M && k < K) ? A[(size_t)m * lda + k] : 0.f;
        }
#pragma unroll
        for (int l = 0; l < 4; l++) {
            int e = l * 256 + tid;
            int kk = e & 15, nn = e >> 4;
            int n = n0 + nn, k = k0 + kk;
            Ws[kk][nn] = (n < N && k < K) ? W[(size_t)n * ldw + woff + k] : 0.f;
        }
        __syncthreads();
#pragma unroll
        for (int kk = 0; kk < 16; kk++) {
            float4 a4 = *(const float4*)&As[kk][ty * 4];
            float4 w4 = *(const float4*)&Ws[kk][tx * 4];
            float av[4] = {a4.x, a4.y, a4.z, a4.w};
            float wv[4] = {w4.x, w4.y, w4.z, w4.w};
#pragma unroll
            for (int i = 0; i < 4; i++)
#pragma unroll
                for (int j = 0; j < 4; j++) acc[i][j] = fmaf(av[i], wv[j], acc[i][j]);
        }
        __syncthreads();
    }
#pragma unroll
    for (int i = 0; i < 4; i++) {
        int m = m0 + ty * 4 + i;
        if (m >= M) continue;
#pragma unroll
        for (int j = 0; j < 4; j++) {
            int n = n0 + tx * 4 + j;
            if (n >= N) continue;
            float val = acc[i][j] + (bias ? bias[n] : 0.f);
            if (mode == 0) C[(size_t)m * N + n] = val;
            else           C[((size_t)(m & 31) * N + n) * 64 + (m >> 5)] = val;
        }
    }
}

// =====================================================================
// Bidirectional GRU recurrence, one time step. grid (256,1,2), block 256.
// Layouts: giT [t][h3][b], hT [t][c][b]. Thread = (dir, j, b).
// =====================================================================
__global__ __launch_bounds__(256) void bigru_step(
    const float* __restrict__ giT_f, const float* __restrict__ giT_b,
    float* __restrict__ hfT, float* __restrict__ hbT,
    const float* __restrict__ Whh_f, const float* __restrict__ Whh_b,
    const float* __restrict__ bhh_f, const float* __restrict__ bhh_b,
    int step)
{
    const int H = Lsz, B = Bsz;
    int dir = blockIdx.z;
    const float* giT = dir ? giT_b : giT_f;
    float* hT        = dir ? hbT   : hfT;
    const float* Whh = dir ? Whh_b : Whh_f;
    const float* bhh = dir ? bhh_b : bhh_f;
    int t = dir ? (Tsz - 1 - step) : step;
    const float* hprev = nullptr;
    if (step > 0) hprev = hT + (size_t)(dir ? (t + 1) : (t - 1)) * H * B;

    int b = threadIdx.x & 63;
    int j = blockIdx.x * 4 + (threadIdx.x >> 6);
    j = __builtin_amdgcn_readfirstlane(j);   // wave-uniform -> scalar W loads

    const float* Wr = Whh + (size_t)j * H;
    const float* Wz = Whh + (size_t)(H + j) * H;
    const float* Wn = Whh + (size_t)(2 * H + j) * H;

    float ar = 0.f, az = 0.f, an = 0.f;
    if (hprev) {
        for (int k = 0; k < H; k += 4) {
#pragma unroll
            for (int u = 0; u < 4; u++) {
                float hv = hprev[(size_t)(k + u) * B + b];
                ar = fmaf(hv, Wr[k + u], ar);
                az = fmaf(hv, Wz[k + u], az);
                an = fmaf(hv, Wn[k + u], an);
            }
        }
    }
    size_t gbase = (size_t)t * H3sz * B + b;
    float gr = giT[gbase + (size_t)j * B];
    float gz = giT[gbase + (size_t)(H + j) * B];
    float gn = giT[gbase + (size_t)(2 * H + j) * B];
    float r = sigf(gr + ar + bhh[j]);
    float z = sigf(gz + az + bhh[H + j]);
    float n = tanhf(gn + r * (an + bhh[2 * H + j]));
    float hp = hprev ? hprev[(size_t)j * B + b] : 0.f;
    float h = (1.f - z) * n + z * hp;
    hT[(size_t)t * H * B + (size_t)j * B + b] = h;
}

// =====================================================================
// txt = (hf+hb)/2, with [t][c][b] -> [b][t][c] transpose through LDS.
// grid (32, 16), block 256.
// =====================================================================
__global__ __launch_bounds__(256) void txt_combine(
    const float* __restrict__ hfT, const float* __restrict__ hbT,
    float* __restrict__ txt)
{
    __shared__ float s[64][65];
    int t = blockIdx.x;
    int c0 = blockIdx.y * 64;
    int tid = threadIdx.x;
#pragma unroll
    for (int l = 0; l < 16; l++) {
        int e = l * 256 + tid;
        int cc = e >> 6, b = e & 63;
        size_t idx = ((size_t)t * Lsz + c0 + cc) * Bsz + b;
        s[cc][b] = 0.5f * (hfT[idx] + hbT[idx]);
    }
    __syncthreads();
#pragma unroll
    for (int l = 0; l < 16; l++) {
        int e = l * 256 + tid;
        int b = e >> 6, cc = e & 63;
        txt[((size_t)b * Tsz + t) * Lsz + c0 + cc] = s[cc][b];
    }
}

// =====================================================================
// Self-attention: logits -> softmax -> apply + residual. grid (64, 8).
// =====================================================================
__global__ __launch_bounds__(256) void attn_kernel(
    const float* __restrict__ q, const float* __restrict__ kmat,
    const float* __restrict__ v, const float* __restrict__ txt,
    const float* __restrict__ gamma_p, float* __restrict__ xattn)
{
    __shared__ float qs[32][129];
    __shared__ float ks[32][129];
    __shared__ float As[32][33];
    int b = blockIdx.x;
    int c0 = blockIdx.y * 128;
    int tid = threadIdx.x;
    for (int e = tid; e < Tsz * Rsz; e += 256) {
        qs[e >> 7][e & 127] = q[(size_t)b * Tsz * Rsz + e];
        ks[e >> 7][e & 127] = kmat[(size_t)b * Tsz * Rsz + e];
    }
    __syncthreads();
    for (int e = tid; e < Tsz * Tsz; e += 256) {
        int t = e >> 5, ss = e & 31;
        float acc = 0.f;
#pragma unroll 4
        for (int o = 0; o < Rsz; o++) acc = fmaf(qs[t][o], ks[ss][o], acc);
        As[t][ss] = acc;
    }
    __syncthreads();
    if (tid < 32) {
        int t = tid;
        float mx = -1e30f;
#pragma unroll
        for (int ss = 0; ss < 32; ss++) mx = fmaxf(mx, As[t][ss]);
        float sum = 0.f;
        float ex[32];
#pragma unroll
        for (int ss = 0; ss < 32; ss++) { ex[ss] = __expf(As[t][ss] - mx); sum += ex[ss]; }
        float inv = 1.f / sum;
#pragma unroll
        for (int ss = 0; ss < 32; ss++) As[t][ss] = ex[ss] * inv;
    }
    __syncthreads();
    float gamma = *gamma_p;
    for (int e = tid; e < Tsz * 128; e += 256) {
        int tt = e >> 7, c = c0 + (e & 127);
        float acc = 0.f;
#pragma unroll 8
        for (int ss = 0; ss < Tsz; ss++)
            acc = fmaf(As[tt][ss], v[((size_t)b * Tsz + ss) * Lsz + c], acc);
        size_t oidx = ((size_t)b * Tsz + tt) * Lsz + c;
        xattn[oidx] = gamma * acc + txt[oidx];
    }
}

// ---------------- length-masked mean pool, grid (64,4) ----------------
__global__ __launch_bounds__(256) void pool_kernel(
    const float* __restrict__ xattn, const int* __restrict__ lens,
    float* __restrict__ txt_embed)
{
    int b = blockIdx.x;
    int c = blockIdx.y * 256 + threadIdx.x;
    int len = lens[b];
    float s = 0.f;
    for (int t = 0; t < len; t++) s += xattn[((size_t)b * Tsz + t) * Lsz + c];
    txt_embed[(size_t)b * Lsz + c] = s / (float)len;
}

// ---------------- image global mean over regions, grid (64,4) ----------------
__global__ __launch_bounds__(256) void imgglob_kernel(
    const float* __restrict__ img_embed, float* __restrict__ img_glob)
{
    int b = blockIdx.x;
    int c = blockIdx.y * 256 + threadIdx.x;
    float s = 0.f;
    for (int r = 0; r < REG; r++) s += img_embed[((size_t)b * REG + r) * Lsz + c];
    img_glob[(size_t)b * Lsz + c] = s * (1.f / (float)REG);
}

// ---------------- iv = l2norm(img_glob) rows, grid 64 ----------------
__global__ __launch_bounds__(256) void ivnorm_kernel(
    const float* __restrict__ img_glob, float* __restrict__ iv)
{
    int i = blockIdx.x;
    int tid = threadIdx.x;
    float s = 0.f;
    for (int c = tid; c < Lsz; c += 256) {
        float x = img_glob[(size_t)i * Lsz + c];
        s += x * x;
    }
#pragma unroll
    for (int off = 32; off; off >>= 1) s += __shfl_down(s, off, 64);
    __shared__ float ps[4];
    if ((tid & 63) == 0) ps[tid >> 6] = s;
    __syncthreads();
    float inv = 1.f / (sqrtf(ps[0] + ps[1] + ps[2] + ps[3]) + 1e-8f);
    for (int c = tid; c < Lsz; c += 256)
        iv[(size_t)i * Lsz + c] = img_glob[(size_t)i * Lsz + c] * inv;
}

// =====================================================================
// Generated-weight GRU step. grid (32, 64 images), block 256.
// capT [t][r][b]; hgenT/hmaxT [i][r][b]; WihAll/WhhAll [i][row][k].
// =====================================================================
__global__ __launch_bounds__(256) void gen_step(
    const float* __restrict__ capT, const float* __restrict__ WihAll,
    const float* __restrict__ WhhAll, const float* __restrict__ bihAll,
    const float* __restrict__ bhhAll, const float* __restrict__ hprevT,
    float* __restrict__ hcurT, float* __restrict__ hmaxT, int t)
{
    const int R = Rsz, B = Bsz;
    int b = threadIdx.x & 63;
    int j = blockIdx.x * 4 + (threadIdx.x >> 6);
    j = __builtin_amdgcn_readfirstlane(j);
    int i = blockIdx.y;
    const float* Wih = WihAll + (size_t)i * R3sz * R;
    const float* Whh = WhhAll + (size_t)i * R3sz * R;
    const float* cap = capT + (size_t)t * R * B;
    const float* hp = hprevT ? hprevT + (size_t)i * R * B : nullptr;
    const float* Wir = Wih + (size_t)j * R;
    const float* Wiz = Wih + (size_t)(R + j) * R;
    const float* Win = Wih + (size_t)(2 * R + j) * R;
    const float* Whr = Whh + (size_t)j * R;
    const float* Whz = Whh + (size_t)(R + j) * R;
    const float* Whn = Whh + (size_t)(2 * R + j) * R;
    float air = 0, aiz = 0, ain = 0, ahr = 0, ahz = 0, ahn = 0;
#pragma unroll 8
    for (int k = 0; k < R; k++) {
        float cv = cap[k * B + b];
        air = fmaf(cv, Wir[k], air);
        aiz = fmaf(cv, Wiz[k], aiz);
        ain = fmaf(cv, Win[k], ain);
    }
    if (hp) {
#pragma unroll 8
        for (int k = 0; k < R; k++) {
            float hv = hp[k * B + b];
            ahr = fmaf(hv, Whr[k], ahr);
            ahz = fmaf(hv, Whz[k], ahz);
            ahn = fmaf(hv, Whn[k], ahn);
        }
    }
    const float* bih = bihAll + (size_t)i * R3sz;
    const float* bhh = bhhAll + (size_t)i * R3sz;
    float r = sigf(air + bih[j] + ahr + bhh[j]);
    float z = sigf(aiz + bih[R + j] + ahz + bhh[R + j]);
    float n = tanhf(ain + bih[2 * R + j] + r * (ahn + bhh[2 * R + j]));
    float hpv = hp ? hp[(size_t)j * B + b] : 0.f;
    float h = (1.f - z) * n + z * hpv;
    size_t idx = ((size_t)i * R + j) * B + b;
    hcurT[idx] = h;
    hmaxT[idx] = (t == 0) ? h : fmaxf(hmaxT[idx], h);
}

// ---------------- hmax [i][j][b] -> [(i*64+b)][j], grid 64 ----------------
__global__ __launch_bounds__(256) void hmax_transpose(
    const float* __restrict__ hmaxT, float* __restrict__ hstd)
{
    __shared__ float s[128][65];
    int i = blockIdx.x, tid = threadIdx.x;
#pragma unroll
    for (int l = 0; l < 32; l++) {
        int e = l * 256 + tid;
        int j = e >> 6, b = e & 63;
        s[j][b] = hmaxT[((size_t)i * Rsz + j) * Bsz + b];
    }
    __syncthreads();
#pragma unroll
    for (int l = 0; l < 32; l++) {
        int e = l * 256 + tid;
        int b = e >> 7, j = e & 127;
        hstd[((size_t)i * Bsz + b) * Rsz + j] = s[j][b];
    }
}

// ---------------- final fused l2norm + cosine, grid 4096 ----------------
__global__ __launch_bounds__(256) void sims_kernel(
    const float* __restrict__ fc_delta, const float* __restrict__ base_fc,
    const float* __restrict__ iv, float* __restrict__ out)
{
    int m = blockIdx.x;          // i*64 + b
    int i = m >> 6, b = m & 63;
    int tid = threadIdx.x;
    float s1 = 0.f, s2 = 0.f;
    for (int c = tid; c < Lsz; c += 256) {
        float f = fc_delta[(size_t)m * Lsz + c] + base_fc[(size_t)b * Lsz + c];
        s1 = fmaf(f, f, s1);
        s2 = fmaf(f, iv[(size_t)i * Lsz + c], s2);
    }
#pragma unroll
    for (int off = 32; off; off >>= 1) {
        s1 += __shfl_down(s1, off, 64);
        s2 += __shfl_down(s2, off, 64);
    }
    __shared__ float p1[4], p2[4];
    int w = tid >> 6;
    if ((tid & 63) == 0) { p1[w] = s1; p2[w] = s2; }
    __syncthreads();
    if (tid == 0) {
        float t1 = p1[0] + p1[1] + p1[2] + p1[3];
        float t2 = p2[0] + p2[1] + p2[2] + p2[3];
        out[m] = t2 / (sqrtf(t1) + 1e-8f);
    }
}

// =====================================================================
extern "C" void kernel_launch(void* const* d_in, const int* in_sizes, int n_in,
                              void* d_out, int out_size, void* d_ws, size_t ws_size,
                              hipStream_t stream)
{
    const float* img_embed    = (const float*)d_in[0];
    const float* cap_embed    = (const float*)d_in[1];
    const int*   lens         = (const int*)d_in[2];
    const float* W_reduce_img = (const float*)d_in[3];
    const float* b_reduce_img = (const float*)d_in[4];
    const float* W_reduce_txt = (const float*)d_in[5];
    const float* b_reduce_txt = (const float*)d_in[6];
    const float* gru_Wih_f    = (const float*)d_in[7];
    const float* gru_Whh_f    = (const float*)d_in[8];
    const float* gru_bih_f    = (const float*)d_in[9];
    const float* gru_bhh_f    = (const float*)d_in[10];
    const float* gru_Wih_b    = (const float*)d_in[11];
    const float* gru_Whh_b    = (const float*)d_in[12];
    const float* gru_bih_b    = (const float*)d_in[13];
    const float* gru_bhh_b    = (const float*)d_in[14];
    const float* sa_Wq        = (const float*)d_in[15];
    const float* sa_bq        = (const float*)d_in[16];
    const float* sa_Wk        = (const float*)d_in[17];
    const float* sa_bk        = (const float*)d_in[18];
    const float* sa_Wv        = (const float*)d_in[19];
    const float* sa_bv        = (const float*)d_in[20];
    const float* sa_gamma     = (const float*)d_in[21];
    const float* gen_Wih      = (const float*)d_in[22];
    const float* gen_bih      = (const float*)d_in[23];
    const float* gen_Whh      = (const float*)d_in[24];
    const float* gen_bhh      = (const float*)d_in[25];
    const float* gen_Wbih     = (const float*)d_in[26];
    const float* gen_bbih     = (const float*)d_in[27];
    const float* gen_Wbhh     = (const float*)d_in[28];
    const float* gen_bbhh     = (const float*)d_in[29];
    const float* W_txt_fc     = (const float*)d_in[30];
    const float* b_txt_fc     = (const float*)d_in[31];

    float* ws = (float*)d_ws;
    size_t off = 0;
    auto alloc = [&](size_t n) { float* p = ws + off; off += n; return p; };
    float* giT_f    = alloc((size_t)Tsz * H3sz * Bsz);   // 6291456
    float* giT_b    = alloc((size_t)Tsz * H3sz * Bsz);
    float* hfT      = alloc((size_t)Tsz * Lsz * Bsz);    // 2097152
    float* hbT      = alloc((size_t)Tsz * Lsz * Bsz);
    float* capT     = alloc((size_t)Tsz * Rsz * Bsz);    // 262144
    float* txt      = alloc((size_t)Bsz * Tsz * Lsz);
    float* qbuf     = alloc((size_t)Bsz * Tsz * Rsz);
    float* kbuf     = alloc((size_t)Bsz * Tsz * Rsz);
    float* vbuf     = alloc((size_t)Bsz * Tsz * Lsz);
    float* xattn    = alloc((size_t)Bsz * Tsz * Lsz);
    float* txt_emb  = alloc((size_t)Bsz * Lsz);
    float* img_glob = alloc((size_t)Bsz * Lsz);
    float* base     = alloc((size_t)Bsz * Rsz);
    float* iv       = alloc((size_t)Bsz * Lsz);
    float* WihAll   = alloc((size_t)Bsz * R3sz * Rsz);   // 3145728
    float* WhhAll   = alloc((size_t)Bsz * R3sz * Rsz);
    float* bihAll   = alloc((size_t)Bsz * R3sz);
    float* bhhAll   = alloc((size_t)Bsz * R3sz);
    float* hA       = alloc((size_t)Bsz * Rsz * Bsz);
    float* hB       = alloc((size_t)Bsz * Rsz * Bsz);
    float* hmaxT    = alloc((size_t)Bsz * Rsz * Bsz);
    float* hstd     = alloc((size_t)Bsz * Bsz * Rsz);
    float* base_fc  = alloc((size_t)Bsz * Lsz);
    float* fc_delta = alloc((size_t)Bsz * Bsz * Lsz);    // 4194304

    // 1) GRU input gates (transposed [t][h3][b]) + cap_reduced ([t][r][b])
    gemm_bias<<<dim3(48, 32), 256, 0, stream>>>(cap_embed, DIN, gru_Wih_f, DIN, 0,
        gru_bih_f, giT_f, Bsz * Tsz, H3sz, DIN, 1);
    gemm_bias<<<dim3(48, 32), 256, 0, stream>>>(cap_embed, DIN, gru_Wih_b, DIN, 0,
        gru_bih_b, giT_b, Bsz * Tsz, H3sz, DIN, 1);
    gemm_bias<<<dim3(2, 32), 256, 0, stream>>>(cap_embed, DIN, W_reduce_txt, DIN, 0,
        b_reduce_txt, capT, Bsz * Tsz, Rsz, DIN, 1);

    // 2) image-side precompute
    imgglob_kernel<<<dim3(64, 4), 256, 0, stream>>>(img_embed, img_glob);
    gemm_bias<<<dim3(2, 1), 256, 0, stream>>>(img_glob, Lsz, W_reduce_img, Lsz, 0,
        b_reduce_img, base, Bsz, Rsz, Lsz, 0);
    ivnorm_kernel<<<64, 256, 0, stream>>>(img_glob, iv);

    // 3) generated weights for all 64 images
    gemm_bias<<<dim3(768, 1), 256, 0, stream>>>(base, Rsz, gen_Wih, Rsz, 0,
        gen_bih, WihAll, Bsz, R3sz * Rsz, Rsz, 0);
    gemm_bias<<<dim3(768, 1), 256, 0, stream>>>(base, Rsz, gen_Whh, Rsz, 0,
        gen_bhh, WhhAll, Bsz, R3sz * Rsz, Rsz, 0);
    gemm_bias<<<dim3(6, 1), 256, 0, stream>>>(base, Rsz, gen_Wbih, Rsz, 0,
        gen_bbih, bihAll, Bsz, R3sz, Rsz, 0);
    gemm_bias<<<dim3(6, 1), 256, 0, stream>>>(base, Rsz, gen_Wbhh, Rsz, 0,
        gen_bbhh, bhhAll, Bsz, R3sz, Rsz, 0);

    // 4) bidirectional GRU recurrence
    for (int s = 0; s < Tsz; s++)
        bigru_step<<<dim3(256, 1, 2), 256, 0, stream>>>(giT_f, giT_b, hfT, hbT,
            gru_Whh_f, gru_Whh_b, gru_bhh_f, gru_bhh_b, s);

    // 5) txt = (hf+hb)/2 -> [b][t][c]
    txt_combine<<<dim3(32, 16), 256, 0, stream>>>(hfT, hbT, txt);

    // 6) self-attention
    gemm_bias<<<dim3(2, 32), 256, 0, stream>>>(txt, Lsz, sa_Wq, Lsz, 0, sa_bq,
        qbuf, Bsz * Tsz, Rsz, Lsz, 0);
    gemm_bias<<<dim3(2, 32), 256, 0, stream>>>(txt, Lsz, sa_Wk, Lsz, 0, sa_bk,
        kbuf, Bsz * Tsz, Rsz, Lsz, 0);
    gemm_bias<<<dim3(16, 32), 256, 0, stream>>>(txt, Lsz, sa_Wv, Lsz, 0, sa_bv,
        vbuf, Bsz * Tsz, Lsz, Lsz, 0);
    attn_kernel<<<dim3(64, 8), 256, 0, stream>>>(qbuf, kbuf, vbuf, txt, sa_gamma, xattn);

    // 7) masked mean pool + image-independent part of the final FC
    pool_kernel<<<dim3(64, 4), 256, 0, stream>>>(xattn, lens, txt_emb);
    gemm_bias<<<dim3(16, 1), 256, 0, stream>>>(txt_emb, Lsz, W_txt_fc, Rsz + Lsz, 0,
        b_txt_fc, base_fc, Bsz, Lsz, Lsz, 0);

    // 8) generated-weight GRU over all images
    for (int t = 0; t < Tsz; t++) {
        const float* hp = (t == 0) ? nullptr : ((t & 1) ? hA : hB);
        float* hc = (t & 1) ? hB : hA;
        gen_step<<<dim3(32, 64), 256, 0, stream>>>(capT, WihAll, WhhAll, bihAll,
            bhhAll, hp, hc, hmaxT, t);
    }
    hmax_transpose<<<64, 256, 0, stream>>>(hmaxT, hstd);

    // 9) per-image FC delta (batched as one GEMM), then fused norm+cosine
    gemm_bias<<<dim3(16, 64), 256, 0, stream>>>(hstd, Rsz, W_txt_fc, Rsz + Lsz, Lsz,
        nullptr, fc_delta, Bsz * Bsz, Lsz, Rsz, 0);
    sims_kernel<<<4096, 256, 0, stream>>>(fc_delta, base_fc, iv, (float*)d_out);
}